// Round 19
// baseline (754.817 us; speedup 1.0000x reference)
//
#include <hip/hip_runtime.h>
#include <hip/hip_fp16.h>

// Bidirectional char-LSTM + masked max-pool via MFMA — DUAL-DIRECTION block.
// 256 blocks = 256 chains; 1024 threads = 16 waves. Waves 0-7 run the FWD
// recurrence of chain b, waves 8-15 the BWD one: two INDEPENDENT dependency
// chains sharing one barrier/step (identical work -> lockstep free). Each
// SIMD holds 2 fwd + 2 bwd waves -> latency of one chain hides under the
// other (R16/R18 lesson: gate-split waves were serially dependent, no hide).
// Per half (= R15/R17 proven): CH=1, 16-dup acc cols; compact Hc[buf][half]
// [192] f16 read as broadcast b128 (chain-free, conflict-free); role-split
// activation (DPP xor8, 6 trans/lane); single-copy dim-pair writeback (DPP
// xor1); 25-lane x staging. NEW: bias rides MFMA -- Hc[k=50] == 1.0 and the
// kt=1 weight frag carries (bih+bhh) at k==50 -> bias4 regs (16) eliminated;
// per-wave regs ~= 96 w + 16 acc + ~14 misc <= 128 -> 16 waves fill the
// register file exactly (occupancy steps at 64/128 per m69).

#define TT 512

typedef _Float16 f16;
typedef _Float16 f16x8 __attribute__((ext_vector_type(8)));
typedef float f32x4 __attribute__((ext_vector_type(4)));
typedef unsigned int u32;
typedef unsigned short u16;

static __device__ __forceinline__ u32 packh2(float lo, float hi) {
    union { struct { f16 x, y; } h; u32 u; } cv;
    cv.h.x = (f16)lo; cv.h.y = (f16)hi;
    return cv.u;
}
static __device__ __forceinline__ float fexp(float x) {
    return __builtin_amdgcn_exp2f(x * 1.44269504088896341f);
}
static __device__ __forceinline__ float frcp(float x) {
    return __builtin_amdgcn_rcpf(x);
}
static __device__ __forceinline__ float sigf(float x) {
    return frcp(1.f + fexp(-x));
}
static __device__ __forceinline__ float xor8(float x) {
    // lane <-> lane^8: DPP row_ror:8 (rotate within rows of 16 == xor 8)
    union { float f; int i; } c; c.f = x;
    c.i = __builtin_amdgcn_mov_dpp(c.i, 0x128, 0xF, 0xF, false);
    return c.f;
}
static __device__ __forceinline__ float xor1(float x) {
    // lane <-> lane^1: quad_perm(1,0,3,2) = 0xB1
    union { float f; int i; } c; c.f = x;
    c.i = __builtin_amdgcn_mov_dpp(c.i, 0xB1, 0xF, 0xF, false);
    return c.f;
}
static __device__ __forceinline__ float sel4(f32x4 v, int q) {
    // q in 0..3, compile-time indices in each arm (no dynamic indexing)
    return (q & 2) ? ((q & 1) ? v[3] : v[2]) : ((q & 1) ? v[1] : v[0]);
}

__global__ __attribute__((amdgpu_flat_work_group_size(1024, 1024),
                          amdgpu_num_vgpr(128)))
void bilstm_dual_kernel(const int* __restrict__ idx,
                        const float* __restrict__ masks,
                        const float* __restrict__ emb,
                        const float* __restrict__ Wih_f, const float* __restrict__ Whh_f,
                        const float* __restrict__ bih_f, const float* __restrict__ bhh_f,
                        const float* __restrict__ Wih_b, const float* __restrict__ Whh_b,
                        const float* __restrict__ bih_b, const float* __restrict__ bhh_b,
                        float* __restrict__ out)
{
    // Hc[buf][half][k]: k 0..49 = x, k 50 = 1.0 (bias lane), 51..63 = 0 pad,
    // 64..191 = h[k-64].  0.75 KB per buf.
    __shared__ __align__(16) u16 Hc[2][2][192];    // 1.5 KB
    __shared__ u16 idx16[TT];                      // 1 KB (shared: same chain)
    __shared__ u32 mbits[TT];                      // 2 KB

    const int tid  = threadIdx.x;
    const int lane = tid & 63;
    const int wv   = tid >> 6;        // wave 0..15
    const int half = wv >> 3;         // 0 = fwd, 1 = bwd (independent chains)
    const int wvh  = wv & 7;
    const int l15  = lane & 15;
    const int c4   = lane >> 4;       // 0..3 (acc row group / B k-group)
    const int b0   = blockIdx.x;      // chain 0..255
    const int rev  = half;

    const int q  = l15 & 3;           // acc row within c4 group (the dim)
    const bool rB = (l15 >> 3) != 0;  // role: A = state-owner, B = helper

    const float* Wih = half ? Wih_b : Wih_f;
    const float* Whh = half ? Whh_b : Whh_f;
    const float* bih = half ? bih_b : bih_f;
    const float* bhh = half ? bhh_b : bhh_f;

    // ---- init: idx (u16), mask bits, Hc = zeros except k==50 -> 1.0
    if (tid < TT) {
        idx16[tid] = (u16)idx[b0 * TT + tid];
        mbits[tid] = (masks[b0 * TT + tid] != 0.f) ? 1u : 0u;
    }
    if (tid < 384) {                       // 2 buf x 2 half x 96 u32
        const int kpair = (tid % 96) * 2;  // element index of the low half
        ((u32*)Hc)[tid] = (kpair == 50) ? 0x00003C00u : 0u;  // f16 1.0 at k=50
    }

    // ---- W fragments (A-operand) in VGPRs: w[kt][gt], gt = i/f/g/o.
    // Lane provides A[row = gate][k]: gate n = (wvh + gt*8)*16 + l15,
    // k = kt*32 + c4*8 + j, j = 0..7. kt=1 embeds bias at k==50.
    f16x8 w[6][4];
#pragma unroll
    for (int gt = 0; gt < 4; ++gt) {
        const int n = (wvh + gt * 8) * 16 + l15;
        // kt = 0: k = c4*8 + j (< 32 < 50) -> Wih (float2 loads)
#pragma unroll
        for (int jj = 0; jj < 4; ++jj) {
            const float2 e = *(const float2*)(Wih + n * 50 + c4 * 8 + jj * 2);
            w[0][gt][2 * jj]     = (f16)e.x;
            w[0][gt][2 * jj + 1] = (f16)e.y;
        }
        // kt = 1: k = 32 + c4*8 + j; k<50 -> Wih; k==50 -> bias; else 0
#pragma unroll
        for (int j = 0; j < 8; ++j) {
            const int k = 32 + c4 * 8 + j;
            float v = 0.f;
            if (k < 50)       v = Wih[n * 50 + k];
            else if (k == 50) v = bih[n] + bhh[n];
            w[1][gt][j] = (f16)v;
        }
        // kt = 2..5: k >= 64 -> Whh[n][k-64] (16B aligned float4 x2)
#pragma unroll
        for (int kt = 2; kt < 6; ++kt) {
            const int kh = (kt - 2) * 32 + c4 * 8;
            const float4 e0 = *(const float4*)(Whh + n * 128 + kh);
            const float4 e1 = *(const float4*)(Whh + n * 128 + kh + 4);
            w[kt][gt][0] = (f16)e0.x; w[kt][gt][1] = (f16)e0.y;
            w[kt][gt][2] = (f16)e0.z; w[kt][gt][3] = (f16)e0.w;
            w[kt][gt][4] = (f16)e1.x; w[kt][gt][5] = (f16)e1.y;
            w[kt][gt][6] = (f16)e1.z; w[kt][gt][7] = (f16)e1.w;
        }
    }

    __syncthreads();   // idx16/mbits/Hc init visible before x store

    // ---- x staging: wave wvh==7 of each half, lanes 0..24 (25 half-pairs)
    const bool xthr = (wvh == 7) && (lane < 25);

    if (xthr) {
        const int t0  = rev ? (TT - 1) : 0;
        const int row = idx16[t0];
        const float2 e = *(const float2*)(emb + row * 50 + lane * 2);
        *(u32*)((unsigned char*)&Hc[0][half][0] + lane * 4) = packh2(e.x, e.y);
    }
    __syncthreads();

    float cst = 0.f, rm = -3e38f;
    const int hd = wvh * 16 + c4 * 4 + q;   // this lane's dim

    for (int s = 0; s < TT; ++s) {
        const int cur = s & 1;
        const int t   = rev ? (TT - 1 - s) : s;

        // prefetch next step's x pair (issued early, hidden under MFMA)
        float2 e;
        const bool pf = xthr && (s + 1 < TT);
        if (pf) {
            const int t1  = rev ? (TT - 2 - s) : (s + 1);
            const int row = idx16[t1];
            e = *(const float2*)(emb + row * 50 + lane * 2);
        }

        // ---- MFMA: 4 gate tiles x 6 K-steps; B-frag = broadcast b128 read
        const unsigned char* hb = (const unsigned char*)&Hc[cur][half][0];
        const f32x4 z = {0.f, 0.f, 0.f, 0.f};
        f32x4 ai = z, af = z, ag = z, ao = z;   // bias comes via k==50
#pragma unroll
        for (int kt = 0; kt < 6; ++kt) {
            const f16x8 bf = *(const f16x8*)(hb + kt * 64 + c4 * 16);
            ai = __builtin_amdgcn_mfma_f32_16x16x32_f16(w[kt][0], bf, ai, 0, 0, 0);
            af = __builtin_amdgcn_mfma_f32_16x16x32_f16(w[kt][1], bf, af, 0, 0, 0);
            ag = __builtin_amdgcn_mfma_f32_16x16x32_f16(w[kt][2], bf, ag, 0, 0, 0);
            ao = __builtin_amdgcn_mfma_f32_16x16x32_f16(w[kt][3], bf, ao, 0, 0, 0);
        }

        // ---- q-row select (cols 16x duplicated -> all lanes valid)
        const float iv = sel4(ai, q);
        const float fv = sel4(af, q);
        const float gv = sel4(ag, q);
        const float ov = sel4(ao, q);

        // ---- SIMT role-split activation, DPP transport (R13-R15 proven):
        // role A: su=sig(f), sv=sig(i); role B: su=sig(2g), sv=sig(o)
        const float u_in = rB ? (gv + gv) : fv;
        const float v_in = rB ? ov : iv;
        const float su = sigf(u_in);
        const float sv = sigf(v_in);
        const float tg_send = 2.f * su - 1.f;     // B: tanh(g); A: junk
        const float tgx = xor8(tg_send);          // A receives tanh(g)
        const float svx = xor8(sv);               // A receives sig(o)
        const float cc = su * cst + sv * tgx;     // A: valid c; B: junk chain
        cst = cc;
        const float ccx = xor8(cc);               // B receives A's cc
        const float cc_use = rB ? ccx : cc;
        const float th = 2.f * sigf(cc_use + cc_use) - 1.f;   // tanh(c)
        const float so_use = rB ? sv : svx;       // sig(o) in both roles
        const float hh = so_use * th;             // VALID in all lanes

        const float pen = mbits[t] ? 0.f : 1e8f;
        rm = fmaxf(rm, hh - pen);

        // ---- writeback: single copy, dim-pair packed via DPP xor1
        unsigned char* nb = (unsigned char*)&Hc[cur ^ 1][half][0];
        const float hx = xor1(hh);                // neighbor dim's h (q^1)
        if (l15 == 0 || l15 == 2) {
            // q even: pk = (h[hd], h[hd+1]); byte 128 + hd*2 is 4B-aligned
            *(u32*)(nb + 128 + hd * 2) = packh2(hh, hx);
        }
        if (pf) {
            *(u32*)(nb + lane * 4) = packh2(e.x, e.y);
        }
        __syncthreads();
    }

    // ---- output: lanes l15 < 4 (q = l15) -> unique dim per lane
    if (l15 < 4) {
        out[b0 * 256 + half * 128 + hd] = rm;
    }
}

extern "C" void kernel_launch(void* const* d_in, const int* in_sizes, int n_in,
                              void* d_out, int out_size, void* d_ws, size_t ws_size,
                              hipStream_t stream) {
    const int*   idx   = (const int*)d_in[0];
    const float* masks = (const float*)d_in[1];
    const float* emb   = (const float*)d_in[2];
    const float* Wih_f = (const float*)d_in[3];
    const float* Whh_f = (const float*)d_in[4];
    const float* bih_f = (const float*)d_in[5];
    const float* bhh_f = (const float*)d_in[6];
    const float* Wih_b = (const float*)d_in[7];
    const float* Whh_b = (const float*)d_in[8];
    const float* bih_b = (const float*)d_in[9];
    const float* bhh_b = (const float*)d_in[10];
    float* out = (float*)d_out;

    bilstm_dual_kernel<<<dim3(256), dim3(1024), 0, stream>>>(
        idx, masks, emb,
        Wih_f, Whh_f, bih_f, bhh_f,
        Wih_b, Whh_b, bih_b, bhh_b,
        out);
}